// Round 1
// baseline (637.882 us; speedup 1.0000x reference)
//
#include <hip/hip_runtime.h>

// Problem dims
#define BB 16
#define NN 4096
#define LL 1024
#define DD 256
#define MTOT (BB*NN)          // 65536 rows
#define EPSV 1e-5f
#define NEGV -1e9f

typedef float f32x4_t __attribute__((ext_vector_type(4)));
typedef short bf16x8_t __attribute__((ext_vector_type(8)));

#define MFMA16(a, b, c) __builtin_amdgcn_mfma_f32_16x16x32_bf16((a), (b), (c), 0, 0, 0)

__device__ __forceinline__ ushort f2bf(float f) {
    unsigned u = __builtin_bit_cast(unsigned, f);
    u += 0x7fffu + ((u >> 16) & 1u);          // RNE
    return (ushort)(u >> 16);
}
__device__ __forceinline__ float bf2f(ushort u) {
    unsigned v = ((unsigned)u) << 16;
    return __builtin_bit_cast(float, v);
}
__device__ __forceinline__ void split1(float f, ushort& hi, ushort& lo) {
    hi = f2bf(f);
    lo = f2bf(f - bf2f(hi));
}
__device__ __forceinline__ float leaky(float v) { return v >= 0.f ? v : 0.2f * v; }

// ---------------- prep kernels ----------------
__global__ __launch_bounds__(256) void prep_split_w1(const float* __restrict__ W1,
                                                     ushort* __restrict__ thi,
                                                     ushort* __restrict__ tlo) {
    int idx = blockIdx.x * 256 + threadIdx.x;   // 262144 = 1024*256
    int k = idx >> 8, d = idx & 255;
    float v = W1[idx];
    ushort hi, lo; split1(v, hi, lo);
    thi[d * 1024 + k] = hi;
    tlo[d * 1024 + k] = lo;
}

__global__ __launch_bounds__(256) void prep_split_w2(const float* __restrict__ W2,
                                                     ushort* __restrict__ thi,
                                                     ushort* __restrict__ tlo) {
    int idx = blockIdx.x * 256 + threadIdx.x;   // 65536
    int k = idx >> 8, d = idx & 255;
    float v = W2[idx];
    ushort hi, lo; split1(v, hi, lo);
    thi[d * 256 + k] = hi;
    tlo[d * 256 + k] = lo;
}

__global__ __launch_bounds__(256) void prep_bn(const float* __restrict__ g,
                                               const float* __restrict__ beta,
                                               const float* __restrict__ mean,
                                               const float* __restrict__ var,
                                               float* __restrict__ scale,
                                               float* __restrict__ shift) {
    int d = threadIdx.x;
    float s = g[d] * rsqrtf(var[d] + EPSV);
    scale[d] = s;
    shift[d] = beta[d] - mean[d] * s;
}

__global__ __launch_bounds__(256) void zero_scores(float* __restrict__ s) {
    s[blockIdx.x * 256 + threadIdx.x] = 0.f;
}

// ---------------- GEMM1: h = leaky(BN(x@W1 + b1)) ----------------
// x [65536,1024] fp32 (split-staged), W1T hi/lo [256][1024] bf16
// tile 128x128, BK=64, 4 waves in 2x2, 3-term split-bf16 MFMA
__global__ __launch_bounds__(256, 2) void gemm1_kernel(const float* __restrict__ x,
                                                       const ushort* __restrict__ Bhi,
                                                       const ushort* __restrict__ Blo,
                                                       const float* __restrict__ b1,
                                                       const float* __restrict__ scale,
                                                       const float* __restrict__ shift,
                                                       float* __restrict__ h) {
    __shared__ ushort sAhi[128 * 64];
    __shared__ ushort sAlo[128 * 64];
    __shared__ ushort sBhi[128 * 64];
    __shared__ ushort sBlo[128 * 64];

    const int tid = threadIdx.x;
    const int lane = tid & 63;
    const int wave = tid >> 6;
    const int wm = wave >> 1, wn = wave & 1;
    const int mblk = blockIdx.x, nblk = blockIdx.y;

    f32x4_t acc[4][4] = {};

    const int ar = tid >> 4;             // 0..15 (A row within sweep)
    const int ac = (tid & 15) * 4;       // A col (floats)
    const int brr = tid >> 3;            // 0..31 (B row within sweep)
    const int bcc = (tid & 7) * 8;       // B col (ushorts)

    const size_t xbase = (size_t)(mblk * 128) * 1024;
    const int dbase = nblk * 128;

    for (int k0 = 0; k0 < 1024; k0 += 64) {
        // stage A (x) with fp32->bf16 hi/lo split, XOR-swizzled LDS
        #pragma unroll
        for (int s = 0; s < 8; ++s) {
            int r = s * 16 + ar;
            float4 v = *reinterpret_cast<const float4*>(x + xbase + (size_t)r * 1024 + k0 + ac);
            int uo = r * 64 + (ac ^ ((r & 7) << 3));
            ushort4 hi, lo;
            split1(v.x, hi.x, lo.x); split1(v.y, hi.y, lo.y);
            split1(v.z, hi.z, lo.z); split1(v.w, hi.w, lo.w);
            *reinterpret_cast<ushort4*>(&sAhi[uo]) = hi;
            *reinterpret_cast<ushort4*>(&sAlo[uo]) = lo;
        }
        // stage B (pre-split W1T rows), 16B copies
        #pragma unroll
        for (int s = 0; s < 4; ++s) {
            int r = s * 32 + brr;
            size_t gsrc = (size_t)(dbase + r) * 1024 + k0 + bcc;
            int uo = r * 64 + (bcc ^ ((r & 7) << 3));
            *reinterpret_cast<uint4*>(&sBhi[uo]) = *reinterpret_cast<const uint4*>(Bhi + gsrc);
            *reinterpret_cast<uint4*>(&sBlo[uo]) = *reinterpret_cast<const uint4*>(Blo + gsrc);
        }
        __syncthreads();
        #pragma unroll
        for (int s = 0; s < 2; ++s) {
            const int kb = s * 32 + (lane >> 4) * 8;
            bf16x8_t aHi[4], aLo[4], bHi[4], bLo[4];
            #pragma unroll
            for (int i = 0; i < 4; ++i) {
                int row = wm * 64 + i * 16 + (lane & 15);
                int uo = row * 64 + (kb ^ ((row & 7) << 3));
                aHi[i] = *reinterpret_cast<const bf16x8_t*>(&sAhi[uo]);
                aLo[i] = *reinterpret_cast<const bf16x8_t*>(&sAlo[uo]);
            }
            #pragma unroll
            for (int j = 0; j < 4; ++j) {
                int col = wn * 64 + j * 16 + (lane & 15);
                int uo = col * 64 + (kb ^ ((col & 7) << 3));
                bHi[j] = *reinterpret_cast<const bf16x8_t*>(&sBhi[uo]);
                bLo[j] = *reinterpret_cast<const bf16x8_t*>(&sBlo[uo]);
            }
            #pragma unroll
            for (int i = 0; i < 4; ++i)
                #pragma unroll
                for (int j = 0; j < 4; ++j) {
                    acc[i][j] = MFMA16(aHi[i], bHi[j], acc[i][j]);
                    acc[i][j] = MFMA16(aHi[i], bLo[j], acc[i][j]);
                    acc[i][j] = MFMA16(aLo[i], bHi[j], acc[i][j]);
                }
        }
        __syncthreads();
    }
    // epilogue: bias + BN + leaky, store h fp32
    #pragma unroll
    for (int j = 0; j < 4; ++j) {
        int col = dbase + wn * 64 + j * 16 + (lane & 15);
        float bj = b1[col], sc = scale[col], sh = shift[col];
        #pragma unroll
        for (int i = 0; i < 4; ++i) {
            int row0 = mblk * 128 + wm * 64 + i * 16 + ((lane >> 4) << 2);
            #pragma unroll
            for (int r = 0; r < 4; ++r) {
                float v = acc[i][j][r] + bj;
                v = v * sc + sh;
                h[(size_t)(row0 + r) * 256 + col] = leaky(v);
            }
        }
    }
}

// ---------------- GEMM2: h2 = leaky(h@W2 + b2); scores += h2 . W3 ----------------
__global__ __launch_bounds__(256, 2) void gemm2_kernel(const float* __restrict__ h,
                                                       const ushort* __restrict__ Bhi,
                                                       const ushort* __restrict__ Blo,
                                                       const float* __restrict__ b2,
                                                       const float* __restrict__ W3,
                                                       float* __restrict__ scores) {
    __shared__ ushort sAhi[128 * 64];
    __shared__ ushort sAlo[128 * 64];
    __shared__ ushort sBhi[128 * 64];
    __shared__ ushort sBlo[128 * 64];

    const int tid = threadIdx.x;
    const int lane = tid & 63;
    const int wave = tid >> 6;
    const int wm = wave >> 1, wn = wave & 1;
    const int mblk = blockIdx.x, nblk = blockIdx.y;

    f32x4_t acc[4][4] = {};

    const int ar = tid >> 4;
    const int ac = (tid & 15) * 4;
    const int brr = tid >> 3;
    const int bcc = (tid & 7) * 8;

    const size_t hbase = (size_t)(mblk * 128) * 256;
    const int dbase = nblk * 128;

    for (int k0 = 0; k0 < 256; k0 += 64) {
        #pragma unroll
        for (int s = 0; s < 8; ++s) {
            int r = s * 16 + ar;
            float4 v = *reinterpret_cast<const float4*>(h + hbase + (size_t)r * 256 + k0 + ac);
            int uo = r * 64 + (ac ^ ((r & 7) << 3));
            ushort4 hi, lo;
            split1(v.x, hi.x, lo.x); split1(v.y, hi.y, lo.y);
            split1(v.z, hi.z, lo.z); split1(v.w, hi.w, lo.w);
            *reinterpret_cast<ushort4*>(&sAhi[uo]) = hi;
            *reinterpret_cast<ushort4*>(&sAlo[uo]) = lo;
        }
        #pragma unroll
        for (int s = 0; s < 4; ++s) {
            int r = s * 32 + brr;
            size_t gsrc = (size_t)(dbase + r) * 256 + k0 + bcc;
            int uo = r * 64 + (bcc ^ ((r & 7) << 3));
            *reinterpret_cast<uint4*>(&sBhi[uo]) = *reinterpret_cast<const uint4*>(Bhi + gsrc);
            *reinterpret_cast<uint4*>(&sBlo[uo]) = *reinterpret_cast<const uint4*>(Blo + gsrc);
        }
        __syncthreads();
        #pragma unroll
        for (int s = 0; s < 2; ++s) {
            const int kb = s * 32 + (lane >> 4) * 8;
            bf16x8_t aHi[4], aLo[4], bHi[4], bLo[4];
            #pragma unroll
            for (int i = 0; i < 4; ++i) {
                int row = wm * 64 + i * 16 + (lane & 15);
                int uo = row * 64 + (kb ^ ((row & 7) << 3));
                aHi[i] = *reinterpret_cast<const bf16x8_t*>(&sAhi[uo]);
                aLo[i] = *reinterpret_cast<const bf16x8_t*>(&sAlo[uo]);
            }
            #pragma unroll
            for (int j = 0; j < 4; ++j) {
                int col = wn * 64 + j * 16 + (lane & 15);
                int uo = col * 64 + (kb ^ ((col & 7) << 3));
                bHi[j] = *reinterpret_cast<const bf16x8_t*>(&sBhi[uo]);
                bLo[j] = *reinterpret_cast<const bf16x8_t*>(&sBlo[uo]);
            }
            #pragma unroll
            for (int i = 0; i < 4; ++i)
                #pragma unroll
                for (int j = 0; j < 4; ++j) {
                    acc[i][j] = MFMA16(aHi[i], bHi[j], acc[i][j]);
                    acc[i][j] = MFMA16(aHi[i], bLo[j], acc[i][j]);
                    acc[i][j] = MFMA16(aLo[i], bHi[j], acc[i][j]);
                }
        }
        __syncthreads();
    }
    // epilogue: leaky(acc+b2) dot W3 per row, butterfly-reduce over 16 col-lanes, atomicAdd
    #pragma unroll
    for (int i = 0; i < 4; ++i) {
        float rowsum[4] = {0.f, 0.f, 0.f, 0.f};
        #pragma unroll
        for (int j = 0; j < 4; ++j) {
            int col = dbase + wn * 64 + j * 16 + (lane & 15);
            float bj = b2[col];
            float w3v = W3[col];
            #pragma unroll
            for (int r = 0; r < 4; ++r) {
                float v = leaky(acc[i][j][r] + bj);
                rowsum[r] += v * w3v;
            }
        }
        int row0 = mblk * 128 + wm * 64 + i * 16 + ((lane >> 4) << 2);
        #pragma unroll
        for (int r = 0; r < 4; ++r) {
            float s = rowsum[r];
            s += __shfl_xor(s, 1);
            s += __shfl_xor(s, 2);
            s += __shfl_xor(s, 4);
            s += __shfl_xor(s, 8);
            if ((lane & 15) == 0) atomicAdd(&scores[row0 + r], s);
        }
    }
}

// ---------------- masked softmax over N per bag; also zeroes M ----------------
__global__ __launch_bounds__(256) void softmax_kernel(const float* __restrict__ scores,
                                                      const int* __restrict__ mask,
                                                      const float* __restrict__ b3,
                                                      float* __restrict__ A,
                                                      float* __restrict__ Mz) {
    int b = blockIdx.x, tid = threadIdx.x;
    __shared__ float red[8];
    float loc[16];
    float mx = -3.4e38f;
    float b3v = b3[0];
    #pragma unroll
    for (int j = 0; j < 16; ++j) {
        int n = j * 256 + tid;
        float s = scores[b * 4096 + n] + b3v;
        if (mask[b * 4096 + n] == 0) s = NEGV;
        loc[j] = s;
        mx = fmaxf(mx, s);
    }
    #pragma unroll
    for (int o = 1; o < 64; o <<= 1) mx = fmaxf(mx, __shfl_xor(mx, o));
    if ((tid & 63) == 0) red[tid >> 6] = mx;
    __syncthreads();
    mx = fmaxf(fmaxf(red[0], red[1]), fmaxf(red[2], red[3]));
    float sum = 0.f;
    #pragma unroll
    for (int j = 0; j < 16; ++j) {
        loc[j] = expf(loc[j] - mx);
        sum += loc[j];
    }
    #pragma unroll
    for (int o = 1; o < 64; o <<= 1) sum += __shfl_xor(sum, o);
    if ((tid & 63) == 0) red[4 + (tid >> 6)] = sum;
    __syncthreads();
    sum = red[4] + red[5] + red[6] + red[7];
    float inv = 1.0f / sum;
    #pragma unroll
    for (int j = 0; j < 16; ++j) A[b * 4096 + j * 256 + tid] = loc[j] * inv;
    // zero the pooled-M buffer for the pool kernel's atomics
    #pragma unroll
    for (int j = 0; j < 4; ++j) Mz[b * 1024 + j * 256 + tid] = 0.f;
}

// ---------------- attention pooling: M[b,:] = sum_n A[b,n] * x[b,n,:] ----------------
__global__ __launch_bounds__(256) void pool_kernel(const float* __restrict__ x,
                                                   const float* __restrict__ A,
                                                   float* __restrict__ M) {
    int b = blockIdx.x, s = blockIdx.y, tid = threadIdx.x;
    __shared__ float sA[64];
    if (tid < 64) sA[tid] = A[b * 4096 + s * 64 + tid];
    __syncthreads();
    float4 acc = {0.f, 0.f, 0.f, 0.f};
    const float* xp = x + ((size_t)b * 4096 + (size_t)s * 64) * 1024 + tid * 4;
    #pragma unroll 4
    for (int n = 0; n < 64; ++n) {
        float a = sA[n];
        float4 v = *reinterpret_cast<const float4*>(xp + (size_t)n * 1024);
        acc.x += a * v.x; acc.y += a * v.y; acc.z += a * v.z; acc.w += a * v.w;
    }
    float* mp = M + b * 1024 + tid * 4;
    atomicAdd(mp + 0, acc.x);
    atomicAdd(mp + 1, acc.y);
    atomicAdd(mp + 2, acc.z);
    atomicAdd(mp + 3, acc.w);
}

// ---------------- classifier + softmax + argmax ----------------
__global__ __launch_bounds__(256) void classifier_kernel(const float* __restrict__ M,
                                                         const float* __restrict__ C1,
                                                         const float* __restrict__ c1,
                                                         const float* __restrict__ C2,
                                                         const float* __restrict__ c2,
                                                         const float* __restrict__ C3,
                                                         const float* __restrict__ c3,
                                                         float* __restrict__ out) {
    int b = blockIdx.x, tid = threadIdx.x;
    __shared__ float sM[1024];
    __shared__ float sZ[256];
    __shared__ float sZ2[256];
    __shared__ float sLg[2];
    #pragma unroll
    for (int j = 0; j < 4; ++j) sM[j * 256 + tid] = M[b * 1024 + j * 256 + tid];
    __syncthreads();
    float a = c1[tid];
    for (int l = 0; l < 1024; ++l) a += sM[l] * C1[l * 256 + tid];
    sZ[tid] = a > 0.f ? a : 0.f;
    __syncthreads();
    float a2 = c2[tid];
    for (int l = 0; l < 256; ++l) a2 += sZ[l] * C2[l * 256 + tid];
    sZ2[tid] = a2 > 0.f ? a2 : 0.f;
    __syncthreads();
    if (tid < 2) {
        float lg = c3[tid];
        for (int l = 0; l < 256; ++l) lg += sZ2[l] * C3[l * 2 + tid];
        sLg[tid] = lg;
    }
    __syncthreads();
    if (tid == 0) {
        float l0 = sLg[0], l1 = sLg[1];
        float mxv = fmaxf(l0, l1);
        float e0 = expf(l0 - mxv), e1 = expf(l1 - mxv);
        float sm = e0 + e1;
        out[b * 2 + 0] = e0 / sm;
        out[b * 2 + 1] = e1 / sm;
        out[32 + b] = (l1 > l0) ? 1.f : 0.f;   // argmax (tie -> 0, matches jnp.argmax)
    }
}

extern "C" void kernel_launch(void* const* d_in, const int* in_sizes, int n_in,
                              void* d_out, int out_size, void* d_ws, size_t ws_size,
                              hipStream_t stream) {
    const float* x        = (const float*)d_in[0];
    const int*   mask     = (const int*)d_in[1];
    const float* W1       = (const float*)d_in[2];
    const float* b1       = (const float*)d_in[3];
    const float* bn_gamma = (const float*)d_in[4];
    const float* bn_beta  = (const float*)d_in[5];
    const float* bn_mean  = (const float*)d_in[6];
    const float* bn_var   = (const float*)d_in[7];
    const float* W2       = (const float*)d_in[8];
    const float* b2       = (const float*)d_in[9];
    const float* W3       = (const float*)d_in[10];
    const float* b3       = (const float*)d_in[11];
    const float* C1       = (const float*)d_in[12];
    const float* c1       = (const float*)d_in[13];
    const float* C2       = (const float*)d_in[14];
    const float* c2       = (const float*)d_in[15];
    const float* C3       = (const float*)d_in[16];
    const float* c3       = (const float*)d_in[17];
    float* out = (float*)d_out;

    // workspace carve-up (~69 MB)
    ushort* w1t_hi  = (ushort*)d_ws;                 // 262144
    ushort* w1t_lo  = w1t_hi + 262144;
    ushort* w2t_hi  = w1t_lo + 262144;               // 65536
    ushort* w2t_lo  = w2t_hi + 65536;
    float*  bn_scale = (float*)(w2t_lo + 65536);     // 256
    float*  bn_shift = bn_scale + 256;               // 256
    float*  scores   = bn_shift + 256;               // 65536
    float*  attnA    = scores + 65536;               // 65536
    float*  Mpool    = attnA + 65536;                // 16384
    float*  h        = Mpool + 16384;                // 16777216 (64 MB)

    prep_split_w1<<<1024, 256, 0, stream>>>(W1, w1t_hi, w1t_lo);
    prep_split_w2<<<256, 256, 0, stream>>>(W2, w2t_hi, w2t_lo);
    prep_bn<<<1, 256, 0, stream>>>(bn_gamma, bn_beta, bn_mean, bn_var, bn_scale, bn_shift);
    zero_scores<<<256, 256, 0, stream>>>(scores);

    gemm1_kernel<<<dim3(512, 2), 256, 0, stream>>>(x, w1t_hi, w1t_lo, b1, bn_scale, bn_shift, h);
    gemm2_kernel<<<dim3(512, 2), 256, 0, stream>>>(h, w2t_hi, w2t_lo, b2, W3, scores);
    softmax_kernel<<<16, 256, 0, stream>>>(scores, mask, b3, attnA, Mpool);
    pool_kernel<<<dim3(16, 64), 256, 0, stream>>>(x, attnA, Mpool);
    classifier_kernel<<<16, 256, 0, stream>>>(Mpool, C1, c1, C2, c2, C3, c3, out);
}

// Round 2
// 626.488 us; speedup vs baseline: 1.0182x; 1.0182x over previous
//
#include <hip/hip_runtime.h>

#define EPSV 1e-5f
#define NEGV -1e9f
#define XRS(r) (((r)&7)<<3)

typedef float f32x4_t __attribute__((ext_vector_type(4)));
typedef short bf16x8_t __attribute__((ext_vector_type(8)));

#define MFMA16(a, b, c) __builtin_amdgcn_mfma_f32_16x16x32_bf16((a), (b), (c), 0, 0, 0)

__device__ __forceinline__ ushort f2bf(float f) {
    unsigned u = __builtin_bit_cast(unsigned, f);
    u += 0x7fffu + ((u >> 16) & 1u);          // RNE
    return (ushort)(u >> 16);
}
__device__ __forceinline__ float bf2f(ushort u) {
    unsigned v = ((unsigned)u) << 16;
    return __builtin_bit_cast(float, v);
}
__device__ __forceinline__ void split1(float f, ushort& hi, ushort& lo) {
    hi = f2bf(f);
    lo = f2bf(f - bf2f(hi));
}
__device__ __forceinline__ float leaky(float v) { return v >= 0.f ? v : 0.2f * v; }

// async global->LDS 16B per lane (linear LDS dest; swizzle pre-baked in global src)
__device__ __forceinline__ void g2lds16(void* lds, const void* g) {
    __builtin_amdgcn_global_load_lds(
        (const __attribute__((address_space(1))) void*)g,
        (__attribute__((address_space(3))) void*)lds, 16, 0, 0);
}

// ---------------- prep: split+tile W1,W2; BN consts; zero scores ----------------
// w1t layout: k0 (=k>>5, 32 tiles) : tile[256 d][64] ushort, entry (d, c=k&31):
//   u = k0*16384 + d*64 + (c ^ XRS(d));  hi at u, lo at u^32
// w2t layout: k0 (=k>>5, 8 tiles) : tile[256 e][64], same formula.
__global__ __launch_bounds__(256) void prep_all(const float* __restrict__ W1,
                                                const float* __restrict__ W2,
                                                const float* __restrict__ g,
                                                const float* __restrict__ be,
                                                const float* __restrict__ mn,
                                                const float* __restrict__ vr,
                                                ushort* __restrict__ w1t,
                                                ushort* __restrict__ w2t,
                                                float* __restrict__ bnsc,
                                                float* __restrict__ bnsh,
                                                float* __restrict__ scores) {
    int blk = blockIdx.x, tid = threadIdx.x;
    if (blk < 1024) {
        int idx = blk * 256 + tid;          // W1 [1024][256]
        int k = idx >> 8, d = idx & 255;
        ushort hi, lo; split1(W1[idx], hi, lo);
        int u = (k >> 5) * 16384 + d * 64 + ((k & 31) ^ XRS(d));
        w1t[u] = hi; w1t[u ^ 32] = lo;
    } else if (blk < 1280) {
        int idx = (blk - 1024) * 256 + tid; // W2 [256][256]
        int k = idx >> 8, e = idx & 255;
        ushort hi, lo; split1(W2[idx], hi, lo);
        int u = (k >> 5) * 16384 + e * 64 + ((k & 31) ^ XRS(e));
        w2t[u] = hi; w2t[u ^ 32] = lo;
    } else if (blk == 1280) {
        float s = g[tid] * rsqrtf(vr[tid] + EPSV);
        bnsc[tid] = s; bnsh[tid] = be[tid] - mn[tid] * s;
    } else {
        int idx = (blk - 1281) * 256 + tid; // 256 blocks -> 65536 scores
        scores[idx] = 0.f;
    }
}

// ---------------- GEMM1: h = leaky(BN(x@W1 + b1)), written split-tiled ----------------
// tile 128x128, BK=32, 4 waves 2x2, 3-term split-bf16 MFMA.
// A (x fp32) reg-staged with in-kernel split; B via global_load_lds from w1t.
// h output layout (for gemm2 A): tile (mblk, k0=col>>5): [128 r][64]:
//   u = (mblk*8+k0)*8192 + r*64 + ((col&31) ^ XRS(r)); hi at u, lo at u^32
__global__ __launch_bounds__(256, 4) void gemm1_kernel(const float* __restrict__ x,
                                                       const ushort* __restrict__ w1t,
                                                       const float* __restrict__ b1,
                                                       const float* __restrict__ bnsc,
                                                       const float* __restrict__ bnsh,
                                                       ushort* __restrict__ hsp) {
    __shared__ ushort sA[128 * 64];
    __shared__ ushort sB[128 * 64];

    const int bid = blockIdx.x;
    const int swz = (bid & 7) * 128 + (bid >> 3);   // XCD-bijective (1024 % 8 == 0)
    const int mblk = swz >> 1, nblk = swz & 1;      // nblk innermost: A-tile pair shares L2
    const int tid = threadIdx.x, lane = tid & 63, wave = tid >> 6;
    const int wm = wave >> 1, wn = wave & 1;

    f32x4_t acc[4][4] = {};

    const int arow = tid >> 3;            // 0..31
    const int acol = (tid & 7) * 4;       // 0..28
    const size_t xbase = (size_t)(mblk * 128) * 1024;
    const ushort* wbase = w1t + nblk * 8192;

    for (int k0 = 0; k0 < 32; ++k0) {
        // B: async DMA 16KB (4 issues x 4KB)
        const ushort* bs = wbase + (size_t)k0 * 16384;
        #pragma unroll
        for (int i = 0; i < 4; ++i)
            g2lds16(&sB[i * 2048 + tid * 8], bs + i * 2048 + tid * 8);
        // A: 4 float4 loads + split + packed hi|lo write (overlaps B DMA)
        #pragma unroll
        for (int s = 0; s < 4; ++s) {
            int r = s * 32 + arow;
            float4 v = *reinterpret_cast<const float4*>(x + xbase + (size_t)r * 1024 + k0 * 32 + acol);
            ushort4 hi, lo;
            split1(v.x, hi.x, lo.x); split1(v.y, hi.y, lo.y);
            split1(v.z, hi.z, lo.z); split1(v.w, hi.w, lo.w);
            int u = r * 64 + (acol ^ XRS(r));
            *reinterpret_cast<ushort4*>(&sA[u]) = hi;
            *reinterpret_cast<ushort4*>(&sA[u ^ 32]) = lo;
        }
        __syncthreads();
        {
            const int g8 = (lane >> 4) * 8;
            bf16x8_t aH[4], aL[4], bH[4], bL[4];
            #pragma unroll
            for (int i = 0; i < 4; ++i) {
                int row = wm * 64 + i * 16 + (lane & 15);
                int u = row * 64 + (g8 ^ XRS(row));
                aH[i] = *reinterpret_cast<const bf16x8_t*>(&sA[u]);
                aL[i] = *reinterpret_cast<const bf16x8_t*>(&sA[u ^ 32]);
            }
            #pragma unroll
            for (int j = 0; j < 4; ++j) {
                int col = wn * 64 + j * 16 + (lane & 15);
                int u = col * 64 + (g8 ^ XRS(col));
                bH[j] = *reinterpret_cast<const bf16x8_t*>(&sB[u]);
                bL[j] = *reinterpret_cast<const bf16x8_t*>(&sB[u ^ 32]);
            }
            #pragma unroll
            for (int i = 0; i < 4; ++i)
                #pragma unroll
                for (int j = 0; j < 4; ++j) {
                    acc[i][j] = MFMA16(aH[i], bH[j], acc[i][j]);
                    acc[i][j] = MFMA16(aH[i], bL[j], acc[i][j]);
                    acc[i][j] = MFMA16(aL[i], bH[j], acc[i][j]);
                }
        }
        __syncthreads();
    }
    // epilogue: bias + BN + leaky -> split -> tiled-swizzled h
    #pragma unroll
    for (int j = 0; j < 4; ++j) {
        int colg = nblk * 128 + wn * 64 + j * 16 + (lane & 15);
        float bj = b1[colg], sc = bnsc[colg], sh = bnsh[colg];
        int cl = colg & 31;
        size_t tbase = ((size_t)mblk * 8 + (colg >> 5)) * 8192;
        #pragma unroll
        for (int i = 0; i < 4; ++i) {
            int rl0 = wm * 64 + i * 16 + ((lane >> 4) << 2);
            #pragma unroll
            for (int r = 0; r < 4; ++r) {
                int rl = rl0 + r;
                float v = leaky((acc[i][j][r] + bj) * sc + sh);
                ushort hi, lo; split1(v, hi, lo);
                int u = rl * 64 + (cl ^ XRS(rl));
                hsp[tbase + u] = hi;
                hsp[tbase + (u ^ 32)] = lo;
            }
        }
    }
}

// ---------------- GEMM2: scores += leaky(h@W2 + b2) . W3 ----------------
// pure-DMA both operands; same tile structure.
__global__ __launch_bounds__(256, 4) void gemm2_kernel(const ushort* __restrict__ hsp,
                                                       const ushort* __restrict__ w2t,
                                                       const float* __restrict__ b2,
                                                       const float* __restrict__ W3,
                                                       float* __restrict__ scores) {
    __shared__ ushort sA[128 * 64];
    __shared__ ushort sB[128 * 64];

    const int bid = blockIdx.x;
    const int swz = (bid & 7) * 128 + (bid >> 3);
    const int mblk = swz >> 1, nblk = swz & 1;
    const int tid = threadIdx.x, lane = tid & 63, wave = tid >> 6;
    const int wm = wave >> 1, wn = wave & 1;

    f32x4_t acc[4][4] = {};

    for (int k0 = 0; k0 < 8; ++k0) {
        const ushort* as = hsp + ((size_t)mblk * 8 + k0) * 8192;
        const ushort* bs = w2t + (size_t)k0 * 16384 + nblk * 8192;
        #pragma unroll
        for (int i = 0; i < 4; ++i) {
            g2lds16(&sA[i * 2048 + tid * 8], as + i * 2048 + tid * 8);
            g2lds16(&sB[i * 2048 + tid * 8], bs + i * 2048 + tid * 8);
        }
        __syncthreads();
        {
            const int g8 = (lane >> 4) * 8;
            bf16x8_t aH[4], aL[4], bH[4], bL[4];
            #pragma unroll
            for (int i = 0; i < 4; ++i) {
                int row = wm * 64 + i * 16 + (lane & 15);
                int u = row * 64 + (g8 ^ XRS(row));
                aH[i] = *reinterpret_cast<const bf16x8_t*>(&sA[u]);
                aL[i] = *reinterpret_cast<const bf16x8_t*>(&sA[u ^ 32]);
            }
            #pragma unroll
            for (int j = 0; j < 4; ++j) {
                int col = wn * 64 + j * 16 + (lane & 15);
                int u = col * 64 + (g8 ^ XRS(col));
                bH[j] = *reinterpret_cast<const bf16x8_t*>(&sB[u]);
                bL[j] = *reinterpret_cast<const bf16x8_t*>(&sB[u ^ 32]);
            }
            #pragma unroll
            for (int i = 0; i < 4; ++i)
                #pragma unroll
                for (int j = 0; j < 4; ++j) {
                    acc[i][j] = MFMA16(aH[i], bH[j], acc[i][j]);
                    acc[i][j] = MFMA16(aH[i], bL[j], acc[i][j]);
                    acc[i][j] = MFMA16(aL[i], bH[j], acc[i][j]);
                }
        }
        __syncthreads();
    }
    // epilogue: leaky(acc+b2) dot W3, 16-lane butterfly, atomic into scores
    #pragma unroll
    for (int i = 0; i < 4; ++i) {
        float rs[4] = {0.f, 0.f, 0.f, 0.f};
        #pragma unroll
        for (int j = 0; j < 4; ++j) {
            int colg = nblk * 128 + wn * 64 + j * 16 + (lane & 15);
            float bj = b2[colg], w3v = W3[colg];
            #pragma unroll
            for (int r = 0; r < 4; ++r)
                rs[r] += leaky(acc[i][j][r] + bj) * w3v;
        }
        int row0 = mblk * 128 + wm * 64 + i * 16 + ((lane >> 4) << 2);
        #pragma unroll
        for (int r = 0; r < 4; ++r) {
            float s = rs[r];
            s += __shfl_xor(s, 1);
            s += __shfl_xor(s, 2);
            s += __shfl_xor(s, 4);
            s += __shfl_xor(s, 8);
            if ((lane & 15) == 0) atomicAdd(&scores[row0 + r], s);
        }
    }
}

// ---------------- masked softmax over N per bag; also zeroes M ----------------
__global__ __launch_bounds__(256) void softmax_kernel(const float* __restrict__ scores,
                                                      const int* __restrict__ mask,
                                                      const float* __restrict__ b3,
                                                      float* __restrict__ A,
                                                      float* __restrict__ Mz) {
    int b = blockIdx.x, tid = threadIdx.x;
    __shared__ float red[8];
    float loc[16];
    float mx = -3.4e38f;
    float b3v = b3[0];
    #pragma unroll
    for (int j = 0; j < 16; ++j) {
        int n = j * 256 + tid;
        float s = scores[b * 4096 + n] + b3v;
        if (mask[b * 4096 + n] == 0) s = NEGV;
        loc[j] = s;
        mx = fmaxf(mx, s);
    }
    #pragma unroll
    for (int o = 1; o < 64; o <<= 1) mx = fmaxf(mx, __shfl_xor(mx, o));
    if ((tid & 63) == 0) red[tid >> 6] = mx;
    __syncthreads();
    mx = fmaxf(fmaxf(red[0], red[1]), fmaxf(red[2], red[3]));
    float sum = 0.f;
    #pragma unroll
    for (int j = 0; j < 16; ++j) {
        loc[j] = expf(loc[j] - mx);
        sum += loc[j];
    }
    #pragma unroll
    for (int o = 1; o < 64; o <<= 1) sum += __shfl_xor(sum, o);
    if ((tid & 63) == 0) red[4 + (tid >> 6)] = sum;
    __syncthreads();
    sum = red[4] + red[5] + red[6] + red[7];
    float inv = 1.0f / sum;
    #pragma unroll
    for (int j = 0; j < 16; ++j) A[b * 4096 + j * 256 + tid] = loc[j] * inv;
    #pragma unroll
    for (int j = 0; j < 4; ++j) Mz[b * 1024 + j * 256 + tid] = 0.f;
}

// ---------------- attention pooling: M[b,:] += sum_n A[b,n] * x[b,n,:] ----------------
__global__ __launch_bounds__(256) void pool_kernel(const float* __restrict__ x,
                                                   const float* __restrict__ A,
                                                   float* __restrict__ M) {
    int b = blockIdx.x, s = blockIdx.y, tid = threadIdx.x;
    __shared__ float sA[128];
    if (tid < 128) sA[tid] = A[b * 4096 + s * 128 + tid];
    __syncthreads();
    float4 acc = {0.f, 0.f, 0.f, 0.f};
    const float* xp = x + ((size_t)b * 4096 + (size_t)s * 128) * 1024 + tid * 4;
    #pragma unroll 8
    for (int n = 0; n < 128; ++n) {
        float a = sA[n];
        float4 v = *reinterpret_cast<const float4*>(xp + (size_t)n * 1024);
        acc.x += a * v.x; acc.y += a * v.y; acc.z += a * v.z; acc.w += a * v.w;
    }
    float* mp = M + b * 1024 + tid * 4;
    atomicAdd(mp + 0, acc.x);
    atomicAdd(mp + 1, acc.y);
    atomicAdd(mp + 2, acc.z);
    atomicAdd(mp + 3, acc.w);
}

// ---------------- classifier + softmax + argmax ----------------
__global__ __launch_bounds__(256) void classifier_kernel(const float* __restrict__ M,
                                                         const float* __restrict__ C1,
                                                         const float* __restrict__ c1,
                                                         const float* __restrict__ C2,
                                                         const float* __restrict__ c2,
                                                         const float* __restrict__ C3,
                                                         const float* __restrict__ c3,
                                                         float* __restrict__ out) {
    int b = blockIdx.x, tid = threadIdx.x;
    __shared__ float sM[1024];
    __shared__ float sZ[256];
    __shared__ float sZ2[256];
    __shared__ float sLg[2];
    #pragma unroll
    for (int j = 0; j < 4; ++j) sM[j * 256 + tid] = M[b * 1024 + j * 256 + tid];
    __syncthreads();
    float a = c1[tid];
    for (int l = 0; l < 1024; ++l) a += sM[l] * C1[l * 256 + tid];
    sZ[tid] = a > 0.f ? a : 0.f;
    __syncthreads();
    float a2 = c2[tid];
    for (int l = 0; l < 256; ++l) a2 += sZ[l] * C2[l * 256 + tid];
    sZ2[tid] = a2 > 0.f ? a2 : 0.f;
    __syncthreads();
    if (tid < 2) {
        float lg = c3[tid];
        for (int l = 0; l < 256; ++l) lg += sZ2[l] * C3[l * 2 + tid];
        sLg[tid] = lg;
    }
    __syncthreads();
    if (tid == 0) {
        float l0 = sLg[0], l1 = sLg[1];
        float mxv = fmaxf(l0, l1);
        float e0 = expf(l0 - mxv), e1 = expf(l1 - mxv);
        float sm = e0 + e1;
        out[b * 2 + 0] = e0 / sm;
        out[b * 2 + 1] = e1 / sm;
        out[32 + b] = (l1 > l0) ? 1.f : 0.f;
    }
}

extern "C" void kernel_launch(void* const* d_in, const int* in_sizes, int n_in,
                              void* d_out, int out_size, void* d_ws, size_t ws_size,
                              hipStream_t stream) {
    const float* x        = (const float*)d_in[0];
    const int*   mask     = (const int*)d_in[1];
    const float* W1       = (const float*)d_in[2];
    const float* b1       = (const float*)d_in[3];
    const float* bn_gamma = (const float*)d_in[4];
    const float* bn_beta  = (const float*)d_in[5];
    const float* bn_mean  = (const float*)d_in[6];
    const float* bn_var   = (const float*)d_in[7];
    const float* W2       = (const float*)d_in[8];
    const float* b2       = (const float*)d_in[9];
    const float* W3       = (const float*)d_in[10];
    const float* b3       = (const float*)d_in[11];
    const float* C1       = (const float*)d_in[12];
    const float* c1       = (const float*)d_in[13];
    const float* C2       = (const float*)d_in[14];
    const float* c2       = (const float*)d_in[15];
    const float* C3       = (const float*)d_in[16];
    const float* c3       = (const float*)d_in[17];
    float* out = (float*)d_out;

    // workspace carve-up (~66 MB)
    ushort* w1t   = (ushort*)d_ws;                   // 524288 (1MB)
    ushort* w2t   = w1t + 524288;                    // 131072 (256KB)
    float*  bnsc  = (float*)(w2t + 131072);          // 256
    float*  bnsh  = bnsc + 256;                      // 256
    float*  scores = bnsh + 256;                     // 65536
    float*  attnA  = scores + 65536;                 // 65536
    float*  Mpool  = attnA + 65536;                  // 16384
    ushort* hsp    = (ushort*)(Mpool + 16384);       // 33554432 (64MB)

    prep_all<<<1537, 256, 0, stream>>>(W1, W2, bn_gamma, bn_beta, bn_mean, bn_var,
                                       w1t, w2t, bnsc, bnsh, scores);
    gemm1_kernel<<<1024, 256, 0, stream>>>(x, w1t, b1, bnsc, bnsh, hsp);
    gemm2_kernel<<<1024, 256, 0, stream>>>(hsp, w2t, b2, W3, scores);
    softmax_kernel<<<16, 256, 0, stream>>>(scores, mask, b3, attnA, Mpool);
    pool_kernel<<<dim3(16, 32), 256, 0, stream>>>(x, attnA, Mpool);
    classifier_kernel<<<16, 256, 0, stream>>>(Mpool, C1, c1, C2, c2, C3, c3, out);
}